// Round 11
// baseline (58.023 us; speedup 1.0000x reference)
//
#include <hip/hip_runtime.h>

typedef __bf16 bf16x8 __attribute__((ext_vector_type(8)));
typedef float  f32x4  __attribute__((ext_vector_type(4)));

#define D100 100
#define NROWS (4096*64)            // 262144 rows of X
#define NTILES (NROWS/16)          // 16384 16-row tiles
#define NCT 7                      // col tiles: 7*16 = 112 >= 100
#define NKS 4                      // k steps: 4*32 = 128 (k=112 = bias row)
#define FRAG_ELEMS (NCT*NKS*64*8)  // 14336 bf16 fragment elements (28672 B)
#define NBLK (NTILES/4)            // 4096 blocks; 4 waves, ONE tile per wave

typedef const __attribute__((address_space(1))) void gvoid;
typedef __attribute__((address_space(3))) void lvoid;

// ---------------------------------------------------------------------------
// Kernel 1: build M = W^T * S in MFMA fragment order (bf16, zero-padded),
// with the bias row folded in at k==112: M[112][n] = (b*S)[n].
// M[k][n] = sum_d W[d*100+k] * S[d*100+n].
// Fragment order: wsM[((ct*4+ks)*64 + lane)*8 + j] holds
//   M[ ks*32 + (lane>>4)*8 + j ][ ct*16 + (lane&15) ]
// ---------------------------------------------------------------------------
__global__ __launch_bounds__(256) void prep_kernel(
    const float* __restrict__ W, const float* __restrict__ bvec,
    const float* __restrict__ S, __bf16* __restrict__ wsM) {
  int tid = blockIdx.x * 256 + threadIdx.x;
  if (tid >= FRAG_ELEMS) return;
  int j    = tid & 7;
  int lane = (tid >> 3) & 63;
  int ks   = (tid >> 9) & 3;
  int ct   = tid >> 11;
  int k = ks * 32 + ((lane >> 4) * 8) + j;
  int n = ct * 16 + (lane & 15);
  float acc = 0.f;
  if (n < D100) {
    if (k < D100) {
      float a0 = 0.f, a1 = 0.f, a2 = 0.f, a3 = 0.f;
      for (int d = 0; d < D100; d += 4) {
        a0 += W[(d + 0) * D100 + k] * S[(d + 0) * D100 + n];
        a1 += W[(d + 1) * D100 + k] * S[(d + 1) * D100 + n];
        a2 += W[(d + 2) * D100 + k] * S[(d + 2) * D100 + n];
        a3 += W[(d + 3) * D100 + k] * S[(d + 3) * D100 + n];
      }
      acc = (a0 + a1) + (a2 + a3);
    } else if (k == 112) {  // bias row
      for (int d = 0; d < D100; ++d) acc += bvec[d] * S[d * D100 + n];
    }
  }
  wsM[tid] = (__bf16)acc;
}

// ---------------------------------------------------------------------------
// Kernel 2: out[r][n] = sum_k x[r][k] * M[k][n]   (bias via M[112], xf=1)
// ZERO-BARRIER variant. Each B fragment is consumed exactly once per
// wave-tile, so LDS-caching M buys nothing: stream B fragments straight
// from global (16B/lane lane-contiguous = 1KB full-line loads, L2-hot --
// 28KB hammered by every CU). x goes to wave-private LDS via linear
// global_load_lds DMA (r8's best input path); the DMA->ds_read dependency
// is enforced by an explicit s_waitcnt vmcnt(0) (+sched_barrier, rule 18),
// NOT __syncthreads -- there are no block-wide barriers at all, so waves
// are fully independent streams (no phase convoys, no slowest-wave
// coupling). 256-thr blocks, LDS 25600B -> 6 blocks/CU; launch_bounds
// (256,6) caps VGPR for 24 waves/CU. Terminal scattered f32x4 store burst
// then exit (r7/r10-measured clean merging, ~1.09x).
// ---------------------------------------------------------------------------
__global__ __launch_bounds__(256, 6) void gemm_kernel(
    const float* __restrict__ x, const __bf16* __restrict__ wsM,
    float* __restrict__ out) {
  __shared__ __align__(16) float ldsX[4 * 1600];  // 25600 B (6400 B/wave)

  const int t    = threadIdx.x;
  const int lane = t & 63;
  const int l16  = lane & 15;
  const int lg   = lane >> 4;
  const int w    = t >> 6;
  const int tile = blockIdx.x * 4 + w;

  // ---- x tile -> wave-private LDS, linear DMA (1KB/instr, full lines) ----
  const char* xsrc = (const char*)x + (size_t)tile * 6400 + (size_t)lane * 16;
  char* ldsx = (char*)(ldsX + w * 1600);
#pragma unroll
  for (int c = 0; c < 6; ++c)
    __builtin_amdgcn_global_load_lds((gvoid*)(xsrc + c * 1024),
                                     (lvoid*)(ldsx + c * 1024), 16, 0, 0);
  if (lane < 16)  // tail bytes 6144..6400
    __builtin_amdgcn_global_load_lds((gvoid*)(xsrc + 6144),
                                     (lvoid*)(ldsx + 6144), 16, 0, 0);

  // own-wave DMA completion; no block barrier (wave-private region)
  asm volatile("s_waitcnt vmcnt(0)" ::: "memory");
  __builtin_amdgcn_sched_barrier(0);

  f32x4 acc[NCT];
#pragma unroll
  for (int ct = 0; ct < NCT; ++ct) acc[ct] = (f32x4){0.f, 0.f, 0.f, 0.f};

  const bf16x8* Bv   = (const bf16x8*)wsM;          // streamed from global
  const float*  xrow = (const float*)ldsx + l16 * D100;

#pragma unroll
  for (int ks = 0; ks < NKS; ++ks) {
    bf16x8 xf;
    if (ks < 3) {
      f32x4 v0 = *(const f32x4*)(xrow + ks * 32 + lg * 8);
      f32x4 v1 = *(const f32x4*)(xrow + ks * 32 + lg * 8 + 4);
#pragma unroll
      for (int j = 0; j < 4; ++j) {
        xf[j]     = (__bf16)v0[j];
        xf[j + 4] = (__bf16)v1[j];
      }
    } else {
      // k = 96 + lg*8 + j: lg==0 -> x[96..99]; lg==2,j==0 (k=112) -> 1.0
      f32x4 v0 = (lg == 0) ? *(const f32x4*)(xrow + 96)
                           : (f32x4){0.f, 0.f, 0.f, 0.f};
#pragma unroll
      for (int j = 0; j < 4; ++j) {
        xf[j]     = (__bf16)v0[j];
        xf[j + 4] = (__bf16)0.f;
      }
      if (lg == 2) xf[0] = (__bf16)1.0f;
    }
#pragma unroll
    for (int ct = 0; ct < NCT; ++ct) {
      bf16x8 bf = Bv[(ct * NKS + ks) * 64 + lane];  // 1KB linear, L2-hot
      acc[ct] = __builtin_amdgcn_mfma_f32_16x16x32_bf16(bf, xf, acc[ct],
                                                        0, 0, 0);
    }
  }

  // ---- tight terminal store burst (lane owns out[l16][ct*16+lg*4..+3]) ----
  float* orow = out + (size_t)tile * (16 * D100) + l16 * D100 + lg * 4;
#pragma unroll
  for (int ct = 0; ct < NCT; ++ct) {
    if (ct < 6 || lg == 0)  // cols 100..111 don't exist
      *(f32x4*)(orow + ct * 16) = acc[ct];
  }
}

extern "C" void kernel_launch(void* const* d_in, const int* in_sizes, int n_in,
                              void* d_out, int out_size, void* d_ws,
                              size_t ws_size, hipStream_t stream) {
  const float* x = (const float*)d_in[0];
  const float* W = (const float*)d_in[1];
  const float* b = (const float*)d_in[2];
  const float* S = (const float*)d_in[3];
  __bf16* wsM = (__bf16*)d_ws;
  float*  out = (float*)d_out;

  hipLaunchKernelGGL(prep_kernel, dim3(56), dim3(256), 0, stream,
                     W, b, S, wsM);
  hipLaunchKernelGGL(gemm_kernel, dim3(NBLK), dim3(256), 0, stream,
                     x, wsM, out);
}

// Round 12
// 45.262 us; speedup vs baseline: 1.2819x; 1.2819x over previous
//
#include <hip/hip_runtime.h>

typedef __bf16 bf16x8 __attribute__((ext_vector_type(8)));
typedef float  f32x4  __attribute__((ext_vector_type(4)));

#define D100 100
#define NROWS (4096*64)            // 262144 rows of X
#define NTILES (NROWS/16)          // 16384 16-row tiles
#define NCT 7                      // col tiles: 7*16 = 112 >= 100
#define NKS 4                      // k steps: 4*32 = 128 (k=112 = bias row)
#define FRAG_ELEMS (NCT*NKS*64*8)  // 14336 bf16 fragment elements (28672 B)
#define TILE_B 6400                // bytes per 16x100 f32 tile
#define NBLK (NTILES/8)            // 2048 blocks; 8 waves, ONE tile per wave

typedef const __attribute__((address_space(1))) void gvoid;
typedef __attribute__((address_space(3))) void lvoid;

// ---------------------------------------------------------------------------
// Kernel 1: build M = W^T * S in MFMA fragment order (bf16, zero-padded),
// with the bias row folded in at k==112: M[112][n] = (b*S)[n].
// M[k][n] = sum_d W[d*100+k] * S[d*100+n].
// Fragment order: wsM[((ct*4+ks)*64 + lane)*8 + j] holds
//   M[ ks*32 + (lane>>4)*8 + j ][ ct*16 + (lane&15) ]
// ---------------------------------------------------------------------------
__global__ __launch_bounds__(256) void prep_kernel(
    const float* __restrict__ W, const float* __restrict__ bvec,
    const float* __restrict__ S, __bf16* __restrict__ wsM) {
  int tid = blockIdx.x * 256 + threadIdx.x;
  if (tid >= FRAG_ELEMS) return;
  int j    = tid & 7;
  int lane = (tid >> 3) & 63;
  int ks   = (tid >> 9) & 3;
  int ct   = tid >> 11;
  int k = ks * 32 + ((lane >> 4) * 8) + j;
  int n = ct * 16 + (lane & 15);
  float acc = 0.f;
  if (n < D100) {
    if (k < D100) {
      float a0 = 0.f, a1 = 0.f, a2 = 0.f, a3 = 0.f;
      for (int d = 0; d < D100; d += 4) {
        a0 += W[(d + 0) * D100 + k] * S[(d + 0) * D100 + n];
        a1 += W[(d + 1) * D100 + k] * S[(d + 1) * D100 + n];
        a2 += W[(d + 2) * D100 + k] * S[(d + 2) * D100 + n];
        a3 += W[(d + 3) * D100 + k] * S[(d + 3) * D100 + n];
      }
      acc = (a0 + a1) + (a2 + a3);
    } else if (k == 112) {  // bias row
      for (int d = 0; d < D100; ++d) acc += bvec[d] * S[d * D100 + n];
    }
  }
  wsM[tid] = (__bf16)acc;
}

// ---------------------------------------------------------------------------
// Kernel 2: out[r][n] = sum_k x[r][k] * M[k][n]   (bias via M[112], xf=1)
// R8 structure (best measured: 45.2us) + NONTEMPORAL linear stores.
// - x -> wave-private LDS via linear global_load_lds DMA (full lines).
// - M fragments -> shared ldsB once per block (hoists B latency off the
//   MFMA critical path; r11 showed streaming B from L2 costs +13us).
// - acc scattered into the consumed wave-private x LDS region, then copied
//   out LINEARLY: 64 lanes x 16B = 8 full 128B lines per instruction.
//   NT is safe here (r4's NT disaster was scattered 64B segments ->
//   partial-line RMW; linear full lines cannot RMW) and frees L3 from
//   105MB of output allocation -> x stays L3-resident (FETCH should drop).
// - Terminal store burst then exit (clean-merge invariant).
// ---------------------------------------------------------------------------
__global__ __launch_bounds__(512, 4) void gemm_kernel(
    const float* __restrict__ x, const __bf16* __restrict__ wsM,
    float* __restrict__ out) {
  __shared__ __align__(16) __bf16 ldsB[FRAG_ELEMS];   // 28672 B
  __shared__ __align__(16) float  ldsX[8 * 1600];     // 51200 B (6400 B/wave)

  const int t    = threadIdx.x;
  const int lane = t & 63;
  const int l16  = lane & 15;
  const int lg   = lane >> 4;
  const int w    = t >> 6;
  const int tile = blockIdx.x * 8 + w;

  // ---- x tile -> LDS, linear (1KB per instruction, full lines) ----
  const char* xsrc = (const char*)x + (size_t)tile * TILE_B + (size_t)lane * 16;
  char* ldsx = (char*)(ldsX + w * 1600);  // wave-private 6400 B
#pragma unroll
  for (int c = 0; c < 6; ++c)
    __builtin_amdgcn_global_load_lds((gvoid*)(xsrc + c * 1024),
                                     (lvoid*)(ldsx + c * 1024), 16, 0, 0);
  if (lane < 16)  // tail: bytes 6144..6400 (2 full lines)
    __builtin_amdgcn_global_load_lds((gvoid*)(xsrc + 6144),
                                     (lvoid*)(ldsx + 6144), 16, 0, 0);

  // ---- M fragments -> LDS, linear (28 x 1KB chunks split across waves) ----
  {
    const char* bsrc = (const char*)wsM + (size_t)lane * 16;
    for (int c = w; c < 28; c += 8)
      __builtin_amdgcn_global_load_lds((gvoid*)(bsrc + c * 1024),
                                       (lvoid*)((char*)ldsB + c * 1024),
                                       16, 0, 0);
  }
  __syncthreads();  // drains vmcnt (all global_load_lds) + syncs ldsB

  f32x4 acc[NCT];
#pragma unroll
  for (int ct = 0; ct < NCT; ++ct) acc[ct] = (f32x4){0.f, 0.f, 0.f, 0.f};

  const bf16x8* Bv = (const bf16x8*)ldsB;
  const char* xrow = ldsx + l16 * 400;

#pragma unroll
  for (int ks = 0; ks < NKS; ++ks) {
    bf16x8 xf;
    if (ks < 3) {
      f32x4 v0 = *(const f32x4*)(xrow + ks * 128 + lg * 32);
      f32x4 v1 = *(const f32x4*)(xrow + ks * 128 + lg * 32 + 16);
#pragma unroll
      for (int j = 0; j < 4; ++j) {
        xf[j]     = (__bf16)v0[j];
        xf[j + 4] = (__bf16)v1[j];
      }
    } else {
      // k = 96 + lg*8 + j: lg==0 -> x[96..99]; lg==2,j==0 (k=112) -> 1.0
      f32x4 v0 = (lg == 0) ? *(const f32x4*)(xrow + 384)
                           : (f32x4){0.f, 0.f, 0.f, 0.f};
#pragma unroll
      for (int j = 0; j < 4; ++j) {
        xf[j]     = (__bf16)v0[j];
        xf[j + 4] = (__bf16)0.f;
      }
      if (lg == 2) xf[0] = (__bf16)1.0f;
    }
#pragma unroll
    for (int ct = 0; ct < NCT; ++ct)
      acc[ct] = __builtin_amdgcn_mfma_f32_16x16x32_bf16(
          Bv[(ct * NKS + ks) * 64 + lane], xf, acc[ct], 0, 0, 0);
  }

  // ---- scatter acc into the (consumed) wave-private x region ----
  // acc[ct][q] = out[row=l16][col=ct*16+lg*4+q] -> byte l16*400+ct*64+lg*16
#pragma unroll
  for (int ct = 0; ct < NCT; ++ct) {
    if (ct < 6 || lg == 0)  // cols 100..111 don't exist
      *(f32x4*)(ldsx + l16 * 400 + ct * 64 + lg * 16) = acc[ct];
  }

  // ---- terminal LINEAR NT store burst (8 full lines/instr), then exit ----
  char* dst = (char*)(out + (size_t)tile * 1600) + (size_t)lane * 16;
#pragma unroll
  for (int c = 0; c < 6; ++c) {
    f32x4 v = *(const f32x4*)(ldsx + c * 1024 + lane * 16);
    __builtin_nontemporal_store(v, (f32x4*)(dst + c * 1024));
  }
  if (lane < 16) {
    f32x4 v = *(const f32x4*)(ldsx + 6144 + lane * 16);
    __builtin_nontemporal_store(v, (f32x4*)(dst + 6144));
  }
}

extern "C" void kernel_launch(void* const* d_in, const int* in_sizes, int n_in,
                              void* d_out, int out_size, void* d_ws,
                              size_t ws_size, hipStream_t stream) {
  const float* x = (const float*)d_in[0];
  const float* W = (const float*)d_in[1];
  const float* b = (const float*)d_in[2];
  const float* S = (const float*)d_in[3];
  __bf16* wsM = (__bf16*)d_ws;
  float*  out = (float*)d_out;

  hipLaunchKernelGGL(prep_kernel, dim3(56), dim3(256), 0, stream,
                     W, b, S, wsM);
  hipLaunchKernelGGL(gemm_kernel, dim3(NBLK), dim3(512), 0, stream,
                     x, wsM, out);
}